// Round 15
// baseline (498.922 us; speedup 1.0000x reference)
//
#include <hip/hip_runtime.h>
#include <hip/hip_bf16.h>

// MultiHeadCrossAttention: B=2,S=2048,D=1024,H=16,HD=64
// prep(cvt emb + transpose weights, fused), merged GEMM(KV+Q -> Kb,Vt,Qb*c)
// on the 128^2 2-phase kernel at 8 waves + VGPR<=64 (r13), flash-attn
// KVBLK=128 r8 body at 8 WAVES / 256-q BLOCKS (r15: 512 thr, 4 q-pair-groups,
// grid 256 -> 4 waves/SIMD [2x] and K/V fetch halved; per-wave work and sync
// skeleton byte-identical to r8), out GEMM 128x64 (r14).

typedef unsigned short ushort;
typedef __attribute__((ext_vector_type(4))) float f32x4;
typedef __attribute__((ext_vector_type(16))) float f32x16;
typedef __attribute__((ext_vector_type(8))) __bf16 bf16x8;
typedef __attribute__((ext_vector_type(8))) unsigned short u16x8;
typedef __attribute__((ext_vector_type(4))) unsigned short u16x4;
typedef __attribute__((ext_vector_type(4))) unsigned int u32x4;

#define LOG2E 1.44269504088896340736f

constexpr int Bc = 2, Sc = 2048, Dc = 1024, Hc = 16, HDc = 64;

__device__ inline ushort f2bf(float f) {
    unsigned u = __builtin_bit_cast(unsigned, f);
    u += 0x7fffu + ((u >> 16) & 1u);   // RNE (inputs finite)
    return (ushort)(u >> 16);
}

__device__ inline float fexp2(float x) {
#if __has_builtin(__builtin_amdgcn_exp2f)
    return __builtin_amdgcn_exp2f(x);   // single v_exp_f32, hazard-safe
#else
    return exp2f(x);
#endif
}

__device__ inline void gload16(const void* g, void* l) {
    __builtin_amdgcn_global_load_lds((const __attribute__((address_space(1))) void*)g,
                                     (__attribute__((address_space(3))) void*)l, 16, 0, 0);
}

__device__ inline f32x4 mfma16(bf16x8 a, bf16x8 b, f32x4 c) {
    return __builtin_amdgcn_mfma_f32_16x16x32_bf16(a, b, c, 0, 0, 0);
}
__device__ inline f32x16 mfma32(bf16x8 a, bf16x8 b, f32x16 c) {
    return __builtin_amdgcn_mfma_f32_32x32x16_bf16(a, b, c, 0, 0, 0);
}
__device__ inline unsigned cvtpk(float lo, float hi_) {
    unsigned r; asm("v_cvt_pk_bf16_f32 %0, %1, %2" : "=v"(r) : "v"(lo), "v"(hi_)); return r;
}
__device__ inline void swap32(unsigned& a, unsigned& b) {
    asm("v_permlane32_swap_b32 %0, %1" : "+v"(a), "+v"(b));
}

// ---- fused preprocessing: emb cvt (blocks 0..2047) + 3 weight transposes ---
__global__ __launch_bounds__(256) void prep_k(const float* __restrict__ emb,
                                              ushort* __restrict__ embb,
                                              const float* __restrict__ Wkv,
                                              const float* __restrict__ Wq,
                                              const float* __restrict__ Wo,
                                              ushort* __restrict__ WtAll) {
    const int bid = blockIdx.x;
    if (bid < 2048) {                     // emb f32 -> bf16, 8 elems/thread
        int i = bid * 256 + threadIdx.x;
        const float4* p = (const float4*)emb;
        float4 a = p[2 * i], b = p[2 * i + 1];
        u16x8 r;
        r[0] = f2bf(a.x); r[1] = f2bf(a.y); r[2] = f2bf(a.z); r[3] = f2bf(a.w);
        r[4] = f2bf(b.x); r[5] = f2bf(b.y); r[6] = f2bf(b.z); r[7] = f2bf(b.w);
        ((u16x8*)embb)[i] = r;
        return;
    }
    // transpose W (K=1024 x N) -> WtAll rows [rowofs, rowofs+N) x 1024, bf16
    __shared__ float t[32][33];
    int tb = bid - 2048;
    const float* W; int N, rowofs;
    if (tb < 2048)      { W = Wkv; N = 2048; rowofs = 0; }
    else if (tb < 3072) { W = Wq;  N = 1024; rowofs = 2048; tb -= 2048; }
    else                { W = Wo;  N = 1024; rowofs = 3072; tb -= 3072; }
    const int nbx = N >> 5;
    const int bx = tb % nbx, by = tb / nbx;
    const int tx = threadIdx.x & 31, ty = threadIdx.x >> 5;
    const int bj = bx * 32, bi = by * 32;
#pragma unroll
    for (int i = 0; i < 4; i++) {
        int r = ty + i * 8;
        t[r][tx] = W[(size_t)(bi + r) * N + bj + tx];
    }
    __syncthreads();
#pragma unroll
    for (int i = 0; i < 4; i++) {
        int r = ty + i * 8;
        WtAll[(size_t)(rowofs + bj + r) * 1024 + bi + tx] = f2bf(t[tx][r]);
    }
}

// ---- GEMM: C[M,N] = A[M,K] @ Bt[N,K]^T + bias (128^2, 8-wave, r13) ---------
// 2-phase counted-vmcnt pipeline: STAGE(next) -> vmcnt(2) -> barrier ->
// ds_read+MFMA -> barrier. 512 thr = 8 waves; acc[2][4] (8 MFMA/iter/wave).
// launch_bounds(512,8) pins VGPR<=64 -> 4 blk/CU = 32 waves/CU.
// MODE 3: merged KV+Q epilogue (direct stores, r8).
template <int MODE>
__global__ __launch_bounds__(512, 8) void gemm_bt_k(const ushort* __restrict__ A,
                                                    const ushort* __restrict__ Bt,
                                                    const float* __restrict__ bias,
                                                    const float* __restrict__ bias2,
                                                    void* __restrict__ Cout,
                                                    ushort* __restrict__ Vout,
                                                    ushort* __restrict__ Qout,
                                                    int M, int N, int K) {
    __shared__ __align__(16) char sA[2][8192];
    __shared__ __align__(16) char sB[2][8192];
    const int tid = threadIdx.x;
    const int nbc = N >> 7;
    const int cpx = (gridDim.x >> 3);
    const int swzb = (blockIdx.x & 7) * cpx + (blockIdx.x >> 3);
    const int brow = swzb / nbc, bcol = swzb % nbc;
    const int w = tid >> 6, lane = tid & 63;
    const int wr = w >> 1, wc = w & 1;
    const int lg = lane >> 4, l16 = lane & 15;

    f32x4 acc[2][4] = {};

    const int r0 = tid >> 2;                   // 0..127
    const int sl = (tid & 3) ^ (r0 & 3);       // pre-swizzled global chunk
    const ushort* a0 = A + (size_t)(brow * 128 + r0) * K + sl * 8;
    const ushort* b0 = Bt + (size_t)(bcol * 128 + r0) * K + sl * 8;

    const int arow = wr * 32 + l16;
    const int bcolr = wc * 64 + l16;

    auto STAGE = [&](int buf, int k0) {
        gload16(a0 + k0, sA[buf] + w * 1024);
        gload16(b0 + k0, sB[buf] + w * 1024);
    };

    const int nk = K >> 5;
    STAGE(0, 0);

    for (int k0 = 0; k0 < nk; k0++) {
        const int buf = k0 & 1;
        if (k0 < nk - 1) {
            STAGE(buf ^ 1, (k0 + 1) << 5);
            asm volatile("s_waitcnt vmcnt(2)" ::: "memory");  // tile k0 landed
        } else {
            asm volatile("s_waitcnt vmcnt(0)" ::: "memory");
        }
        __builtin_amdgcn_s_barrier();
        __builtin_amdgcn_sched_barrier(0);

        bf16x8 af[2], bfr[4];
#pragma unroll
        for (int rf = 0; rf < 2; rf++) {
            int rr = arow + rf * 16;
            af[rf] = *(const bf16x8*)(sA[buf] + rr * 64 + ((lg * 16) ^ ((rr & 3) << 4)));
        }
#pragma unroll
        for (int cf = 0; cf < 4; cf++) {
            int rr = bcolr + cf * 16;
            bfr[cf] = *(const bf16x8*)(sB[buf] + rr * 64 + ((lg * 16) ^ ((rr & 3) << 4)));
        }
#pragma unroll
        for (int rf = 0; rf < 2; rf++)
#pragma unroll
            for (int cf = 0; cf < 4; cf++)
                acc[rf][cf] = mfma16(af[rf], bfr[cf], acc[rf][cf]);
        __builtin_amdgcn_s_barrier();     // reads done before buf is re-staged
    }

#pragma unroll
    for (int cf = 0; cf < 4; cf++) {
        const int col = bcol * 128 + wc * 64 + cf * 16 + l16;
        if constexpr (MODE == 3) {
            if (col < 2048) {          // KV region (uniform per block: bcol<16)
                const float bv = bias[col];
                const int h = col >> 7, lo = col & 127;
#pragma unroll
                for (int rf = 0; rf < 2; rf++) {
                    int row = brow * 128 + wr * 32 + rf * 16 + lg * 4;
                    int b = row >> 11, s = row & 2047;
                    if (lo < 64) {   // K -> Kb[bh][s][d]
                        ushort* Kout = (ushort*)Cout;
#pragma unroll
                        for (int r = 0; r < 4; r++)
                            Kout[((size_t)(b * 16 + h) * 2048 + s + r) * 64 + lo] =
                                f2bf(acc[rf][cf][r] + bv);
                    } else {         // V -> Vt[bh][d][s], 4 s-values packed
                        u16x4 pk;
#pragma unroll
                        for (int r = 0; r < 4; r++) pk[r] = f2bf(acc[rf][cf][r] + bv);
                        *(u16x4*)(Vout + ((size_t)(b * 16 + h) * 64 + (lo - 64)) * 2048 + s) = pk;
                    }
                }
            } else {                   // Q region: scale by 0.125*log2e (exp2 fold)
                const int qc = col - 2048;
                const float bv = bias2[qc];
                const float qs = 0.125f * LOG2E;
#pragma unroll
                for (int rf = 0; rf < 2; rf++) {
                    int row = brow * 128 + wr * 32 + rf * 16 + lg * 4;
#pragma unroll
                    for (int r = 0; r < 4; r++)
                        Qout[(size_t)(row + r) * 1024 + qc] =
                            f2bf((acc[rf][cf][r] + bv) * qs);
                }
            }
        } else {
            const float bv = bias[col];
#pragma unroll
            for (int rf = 0; rf < 2; rf++) {
                int row = brow * 128 + wr * 32 + rf * 16 + lg * 4;
#pragma unroll
                for (int r = 0; r < 4; r++) {
                    float v = acc[rf][cf][r] + bv;
                    if (MODE == 1) ((float*)Cout)[(size_t)(row + r) * N + col] = v;
                    else           ((ushort*)Cout)[(size_t)(row + r) * N + col] = f2bf(v);
                }
            }
        }
    }
}

// ---- out-projection GEMM: 128x64 tiles, grid 512 (r14-verified) ------------
__global__ __launch_bounds__(256, 8) void gemm_out_k(const ushort* __restrict__ A,
                                                     const ushort* __restrict__ Bt,
                                                     const float* __restrict__ bias,
                                                     float* __restrict__ Cout,
                                                     int N, int K) {
    __shared__ __align__(16) char sA[2][8192];   // 128 rows x 32 k
    __shared__ __align__(16) char sB[2][4096];   // 64 rows x 32 k
    const int tid = threadIdx.x;
    const int nbc = N >> 6;                       // 16
    const int cpx = (gridDim.x >> 3);             // 512 -> 64 (grid%8==0)
    const int swzb = (blockIdx.x & 7) * cpx + (blockIdx.x >> 3);
    const int brow = swzb / nbc, bcol = swzb % nbc;
    const int w = tid >> 6, lane = tid & 63;
    const int lg = lane >> 4, l16 = lane & 15;

    f32x4 acc[2][4] = {};

    const int r0 = tid >> 2;                   // 0..63
    const int sl = (tid & 3) ^ (r0 & 3);       // pre-swizzled global chunk
    const ushort* a0 = A + (size_t)(brow * 128 + r0) * K + sl * 8;
    const ushort* a1 = A + (size_t)(brow * 128 + 64 + r0) * K + sl * 8;  // (64&3)==0
    const ushort* b0 = Bt + (size_t)(bcol * 64 + r0) * K + sl * 8;

    const int arow = w * 32 + l16;

    auto STAGE = [&](int buf, int k0) {
        gload16(a0 + k0, sA[buf] + w * 1024);
        gload16(a1 + k0, sA[buf] + 4096 + w * 1024);
        gload16(b0 + k0, sB[buf] + w * 1024);
    };

    const int nk = K >> 5;                     // 32
    STAGE(0, 0);

    for (int k0 = 0; k0 < nk; k0++) {
        const int buf = k0 & 1;
        if (k0 < nk - 1) {
            STAGE(buf ^ 1, (k0 + 1) << 5);
            asm volatile("s_waitcnt vmcnt(3)" ::: "memory");  // tile k0 landed
        } else {
            asm volatile("s_waitcnt vmcnt(0)" ::: "memory");
        }
        __builtin_amdgcn_s_barrier();
        __builtin_amdgcn_sched_barrier(0);

        bf16x8 af[2], bfr[4];
#pragma unroll
        for (int rf = 0; rf < 2; rf++) {
            int rr = arow + rf * 16;
            af[rf] = *(const bf16x8*)(sA[buf] + rr * 64 + ((lg * 16) ^ ((rr & 3) << 4)));
        }
#pragma unroll
        for (int cf = 0; cf < 4; cf++) {
            int rr = cf * 16 + l16;
            bfr[cf] = *(const bf16x8*)(sB[buf] + rr * 64 + ((lg * 16) ^ ((rr & 3) << 4)));
        }
#pragma unroll
        for (int rf = 0; rf < 2; rf++)
#pragma unroll
            for (int cf = 0; cf < 4; cf++)
                acc[rf][cf] = mfma16(af[rf], bfr[cf], acc[rf][cf]);
        __builtin_amdgcn_s_barrier();     // reads done before buf is re-staged
    }

#pragma unroll
    for (int cf = 0; cf < 4; cf++) {
        const int col = bcol * 64 + cf * 16 + l16;
        const float bv = bias[col];
#pragma unroll
        for (int rf = 0; rf < 2; rf++) {
            int row = brow * 128 + w * 32 + rf * 16 + lg * 4;
#pragma unroll
            for (int r = 0; r < 4; r++)
                Cout[(size_t)(row + r) * N + col] = acc[rf][cf][r] + bv;
        }
    }
}

// ---- flash attention, KVBLK=128, 8 waves / 256-q blocks (r15) --------------
// Grid 256 = 32 bh x 8 qtiles(256). 8 waves = 4 pairs; pair (w>>1) owns
// 64 q-cols, member (w&1) owns kk chunks {ksub*32 + kh*64} per tile.
// Per-wave body identical to r8; sync skeleton identical (STAGE -> counted
// vmcnt -> barrier -> compute -> barrier). 512 thr stage the same 32KB tile
// -> 4 gload16/thread, vmcnt(4). 4 waves/SIMD (2x r8); K/V fetch halved.
__global__ __launch_bounds__(512, 4) void attn3_k(const ushort* __restrict__ Qg,
                                                  const ushort* __restrict__ Kg,
                                                  const ushort* __restrict__ Vg,
                                                  ushort* __restrict__ ctx) {
    __shared__ __align__(16) char sK[2][16384];  // [128 kk][64 d], 128B rows, XOR-swz
    __shared__ __align__(16) char sV[2][16384];  // [2 kh][64 d][64 kk], 128B rows, XOR-swz
    __shared__ float lx2[512];                   // l exchange (8 q-groups x 64 lanes)
    const int tid = threadIdx.x;
    const int wg = ((blockIdx.x & 7) << 5) | (blockIdx.x >> 3);   // XCD swizzle, 256%8==0
    const int bh = wg >> 3, qt = wg & 7;
    const int b = bh >> 4, h = bh & 15;
    const int w = tid >> 6, lane = tid & 63;
    const int ql = lane & 31, hi = lane >> 5;
    const int ksub = w & 1;          // which 32-kk subchunk (per kh) this wave owns
    const int qq = w >> 1;           // which 64 q-cols this wave pair owns (0..3)

    const ushort* Kh = Kg + (size_t)bh * (Sc * 64);
    const ushort* Vh = Vg + (size_t)bh * (64 * Sc);

    // Q fragments for two 32-col groups (B-operand: col=q, 8 contig d/lane-half)
    const int qrow0 = qt * 256 + qq * 64 + ql;
    bf16x8 qf[2][4];
#pragma unroll
    for (int qg = 0; qg < 2; qg++) {
        const ushort* qp = Qg + ((size_t)(b * Sc + qrow0 + qg * 32)) * Dc + h * HDc + hi * 8;
#pragma unroll
        for (int jd = 0; jd < 4; jd++) qf[qg][jd] = *(const bf16x8*)(qp + jd * 16);
    }

    const int l8 = lane >> 3;                    // row&7 of every staged row
    const int sl = (lane & 7) ^ l8;              // pre-swizzled chunk

    f32x16 o[2][2] = {};     // [dg][qg]
    float l_run[2] = {0.0f, 0.0f};               // row-sum l (f32, per q-group)
    const float MH = 8.0f * LOG2E;
    const int sw = (ql & 7) << 4;                // read-side XOR swizzle

    // staging (512 thr, 4 gload16/thread):
    //  K: rows w*16 + j*8 + l8 (j=0..1) cover 0..127; chunk slot lane&7 holds
    //     global chunk sl = (lane&7)^(row&7); dest sK + w*2048 + j*1024.
    //  V: kh = w>>2; d-rows (w&3)*16 + j*8 + l8 cover 0..63;
    //     dest sV + kh*8192 + (w&3)*2048 + j*1024.
    auto STAGE = [&](int buf, int kt) {
#pragma unroll
        for (int j = 0; j < 2; j++) {
            gload16(Kh + (size_t)(kt * 128 + w * 16 + j * 8 + l8) * 64 + sl * 8,
                    sK[buf] + w * 2048 + j * 1024);
            gload16(Vh + (size_t)((w & 3) * 16 + j * 8 + l8) * Sc +
                        kt * 128 + (w >> 2) * 64 + sl * 8,
                    sV[buf] + (w >> 2) * 8192 + (w & 3) * 2048 + j * 1024);
        }
    };

    int cur = 0;
    STAGE(0, 0);

    constexpr int NT = Sc / 128;     // 16
    for (int kt = 0; kt < NT; kt++) {
        if (kt < NT - 1) {
            STAGE(cur ^ 1, kt + 1);
            asm volatile("s_waitcnt vmcnt(4)" ::: "memory");   // tile kt complete
        } else {
            asm volatile("s_waitcnt vmcnt(0)" ::: "memory");
        }
        __builtin_amdgcn_s_barrier();
        __builtin_amdgcn_sched_barrier(0);

#pragma unroll
        for (int kh = 0; kh < 2; kh++) {
            bf16x8 kf[4];
            {
                const char* kb = sK[cur] + (kh * 64 + ksub * 32 + ql) * 128;
#pragma unroll
                for (int jd = 0; jd < 4; jd++)
                    kf[jd] = *(const bf16x8*)(kb + ((jd * 32 + hi * 16) ^ sw));
            }

            f32x16 st[2];
#pragma unroll
            for (int qg = 0; qg < 2; qg++)
#pragma unroll
                for (int i = 0; i < 16; i++) st[qg][i] = -MH;
            __builtin_amdgcn_s_setprio(1);
#pragma unroll
            for (int qg = 0; qg < 2; qg++)
#pragma unroll
                for (int jd = 0; jd < 4; jd++)
                    st[qg] = mfma32(kf[jd], qf[qg][jd], st[qg]);
            __builtin_amdgcn_s_setprio(0);

#pragma unroll
            for (int qg = 0; qg < 2; qg++)
#pragma unroll
                for (int i = 0; i < 16; i++) st[qg][i] = fexp2(st[qg][i]);

            // row-sum l (VALU): partner lane (hi^1) holds the other 16 rows
#pragma unroll
            for (int qg = 0; qg < 2; qg++) {
                float s = ((st[qg][0] + st[qg][1]) + (st[qg][2] + st[qg][3])) +
                          ((st[qg][4] + st[qg][5]) + (st[qg][6] + st[qg][7])) +
                          (((st[qg][8] + st[qg][9]) + (st[qg][10] + st[qg][11])) +
                           ((st[qg][12] + st[qg][13]) + (st[qg][14] + st[qg][15])));
                l_run[qg] += s + __shfl_xor(s, 32);
            }

            bf16x8 pf[2][2];
#pragma unroll
            for (int qg = 0; qg < 2; qg++) {
                unsigned a0 = cvtpk(st[qg][0],  st[qg][1]);
                unsigned a1 = cvtpk(st[qg][2],  st[qg][3]);
                unsigned a2 = cvtpk(st[qg][4],  st[qg][5]);
                unsigned a3 = cvtpk(st[qg][6],  st[qg][7]);
                swap32(a0, a2); swap32(a1, a3);
                u32x4 f0v = {a0, a1, a2, a3};
                pf[qg][0] = __builtin_bit_cast(bf16x8, f0v);
                unsigned c0 = cvtpk(st[qg][8],  st[qg][9]);
                unsigned c1 = cvtpk(st[qg][10], st[qg][11]);
                unsigned c2 = cvtpk(st[qg][12], st[qg][13]);
                unsigned c3 = cvtpk(st[qg][14], st[qg][15]);
                swap32(c0, c2); swap32(c1, c3);
                u32x4 f1v = {c0, c1, c2, c3};
                pf[qg][1] = __builtin_bit_cast(bf16x8, f1v);
            }

            bf16x8 vf[2][2];   // [dg][ks]
#pragma unroll
            for (int dg = 0; dg < 2; dg++) {
                const char* vb = sV[cur] + kh * 8192 + (dg * 32 + ql) * 128;
#pragma unroll
                for (int ks = 0; ks < 2; ks++)
                    vf[dg][ks] = *(const bf16x8*)(vb + ((ksub * 64 + ks * 32 + hi * 16) ^ sw));
            }

            __builtin_amdgcn_s_setprio(1);
#pragma unroll
            for (int qg = 0; qg < 2; qg++)
#pragma unroll
                for (int ks = 0; ks < 2; ks++) {
                    o[0][qg] = mfma32(vf[0][ks], pf[qg][ks], o[0][qg]);
                    o[1][qg] = mfma32(vf[1][ks], pf[qg][ks], o[1][qg]);
                }
            __builtin_amdgcn_s_setprio(0);
        }

        __builtin_amdgcn_s_barrier();     // protect buffer reuse (no vmem drain)
        cur ^= 1;
    }

    // cross-wave (pair) combine: waves ksub=1 export, ksub=0 reduce + write.
    // Pair qq's 16KB region: qq<2 -> sK half qq; qq>=2 -> sV half (qq-2).
    __syncthreads();                      // full sync before LDS reuse
    float* ox = (float*)((qq < 2 ? (char*)sK : (char*)sV) + (qq & 1) * 16384);
    if (ksub) {
#pragma unroll
        for (int dg = 0; dg < 2; dg++)
#pragma unroll
            for (int qg = 0; qg < 2; qg++)
#pragma unroll
                for (int i = 0; i < 16; i++)
                    ox[((dg * 2 + qg) * 16 + i) * 64 + lane] = o[dg][qg][i];
        lx2[(qq * 2 + 0) * 64 + lane] = l_run[0];
        lx2[(qq * 2 + 1) * 64 + lane] = l_run[1];
    }
    __syncthreads();
    if (!ksub) {
#pragma unroll
        for (int dg = 0; dg < 2; dg++)
#pragma unroll
            for (int qg = 0; qg < 2; qg++)
#pragma unroll
                for (int i = 0; i < 16; i++)
                    o[dg][qg][i] += ox[((dg * 2 + qg) * 16 + i) * 64 + lane];
        const float inv0 = 1.0f / (l_run[0] + lx2[(qq * 2 + 0) * 64 + lane]);
        const float inv1 = 1.0f / (l_run[1] + lx2[(qq * 2 + 1) * 64 + lane]);
#pragma unroll
        for (int qg = 0; qg < 2; qg++) {
            const float inv = qg ? inv1 : inv0;
            ushort* cp = ctx + ((size_t)(b * Sc + qrow0 + qg * 32)) * Dc + h * HDc;
#pragma unroll
            for (int dg = 0; dg < 2; dg++)
#pragma unroll
                for (int g = 0; g < 4; g++) {
                    u16x4 pk;
#pragma unroll
                    for (int r = 0; r < 4; r++)
                        pk[r] = f2bf(o[dg][qg][g * 4 + r] * inv);
                    *(u16x4*)(cp + dg * 32 + g * 8 + hi * 4) = pk;
                }
        }
    }
}

extern "C" void kernel_launch(void* const* d_in, const int* in_sizes, int n_in,
                              void* d_out, int out_size, void* d_ws, size_t ws_size,
                              hipStream_t stream) {
    const float* emb  = (const float*)d_in[0];
    const float* W_kv = (const float*)d_in[1];
    const float* b_kv = (const float*)d_in[2];
    const float* W_q  = (const float*)d_in[3];
    const float* b_q  = (const float*)d_in[4];
    const float* W_o  = (const float*)d_in[5];
    const float* b_o  = (const float*)d_in[6];
    float* out = (float*)d_out;

    const int BS = Bc * Sc;           // 4096 rows
    ushort* embb  = (ushort*)d_ws;                      // 4096x1024
    ushort* wallt = embb  + (size_t)BS * Dc;            // 4096x1024 (Wkv^T|Wq^T|Wo^T)
    ushort* wot   = wallt + (size_t)3 * Dc * Dc;        // alias: rows 3072..4095
    ushort* Kb    = wallt + (size_t)4 * Dc * Dc;        // 32 x 2048 x 64
    ushort* Vtb   = Kb    + (size_t)32 * Sc * HDc;      // 32 x 64 x 2048
    ushort* Qb    = Vtb   + (size_t)32 * Sc * HDc;      // 4096x1024 (pre-scaled)
    ushort* ctxb  = Qb    + (size_t)BS * Dc;            // 4096x1024
    // total ~48 MB of d_ws

    prep_k<<<6144, 256, 0, stream>>>(emb, embb, W_kv, W_q, W_o, wallt);

    // merged KV+Q projection: 128^2 tiles, 8 waves, N = 3072, grid 768 (%8==0)
    gemm_bt_k<3><<<(BS / 128) * (3072 / 128), 512, 0, stream>>>(
        embb, wallt, b_kv, b_q, Kb, Vtb, Qb, BS, 3072, Dc);

    // KVBLK=128 attn: 256 q-rows per block, 8 waves, grid 256 (%8==0)
    attn3_k<<<Bc * Hc * (Sc / 256), 512, 0, stream>>>(Qb, Kb, Vtb, ctxb);

    // out projection: 128x64 tiles, grid 512 (%8==0), 2 blk/CU
    gemm_out_k<<<(BS / 128) * (Dc / 64), 256, 0, stream>>>(
        ctxb, wot, b_o, out, Dc, Dc);
}

// Round 16
// 108.121 us; speedup vs baseline: 4.6145x; 4.6145x over previous
//
#include <hip/hip_runtime.h>
#include <hip/hip_bf16.h>

// MultiHeadCrossAttention: B=2,S=2048,D=1024,H=16,HD=64
// prep(cvt emb + transpose weights, fused), merged GEMM(KV+Q -> Kb,Vt,Qb*c)
// on the 128^2 2-phase kernel at 8 waves + VGPR<=64 (r13), flash-attn
// KVBLK=128 r8 body at 8 WAVES / 256-q BLOCKS (r16 = r15 with the launch
// bound fixed: (512,2) -> VGPR cap 128 fits the ~124-reg body; LDS-limited
// 2 blk/CU = 4 waves/SIMD, 2x r8 TLP; K/V fetch halved), out GEMM 128x64.

typedef unsigned short ushort;
typedef __attribute__((ext_vector_type(4))) float f32x4;
typedef __attribute__((ext_vector_type(16))) float f32x16;
typedef __attribute__((ext_vector_type(8))) __bf16 bf16x8;
typedef __attribute__((ext_vector_type(8))) unsigned short u16x8;
typedef __attribute__((ext_vector_type(4))) unsigned short u16x4;
typedef __attribute__((ext_vector_type(4))) unsigned int u32x4;

#define LOG2E 1.44269504088896340736f

constexpr int Bc = 2, Sc = 2048, Dc = 1024, Hc = 16, HDc = 64;

__device__ inline ushort f2bf(float f) {
    unsigned u = __builtin_bit_cast(unsigned, f);
    u += 0x7fffu + ((u >> 16) & 1u);   // RNE (inputs finite)
    return (ushort)(u >> 16);
}

__device__ inline float fexp2(float x) {
#if __has_builtin(__builtin_amdgcn_exp2f)
    return __builtin_amdgcn_exp2f(x);   // single v_exp_f32, hazard-safe
#else
    return exp2f(x);
#endif
}

__device__ inline void gload16(const void* g, void* l) {
    __builtin_amdgcn_global_load_lds((const __attribute__((address_space(1))) void*)g,
                                     (__attribute__((address_space(3))) void*)l, 16, 0, 0);
}

__device__ inline f32x4 mfma16(bf16x8 a, bf16x8 b, f32x4 c) {
    return __builtin_amdgcn_mfma_f32_16x16x32_bf16(a, b, c, 0, 0, 0);
}
__device__ inline f32x16 mfma32(bf16x8 a, bf16x8 b, f32x16 c) {
    return __builtin_amdgcn_mfma_f32_32x32x16_bf16(a, b, c, 0, 0, 0);
}
__device__ inline unsigned cvtpk(float lo, float hi_) {
    unsigned r; asm("v_cvt_pk_bf16_f32 %0, %1, %2" : "=v"(r) : "v"(lo), "v"(hi_)); return r;
}
__device__ inline void swap32(unsigned& a, unsigned& b) {
    asm("v_permlane32_swap_b32 %0, %1" : "+v"(a), "+v"(b));
}

// ---- fused preprocessing: emb cvt (blocks 0..2047) + 3 weight transposes ---
__global__ __launch_bounds__(256) void prep_k(const float* __restrict__ emb,
                                              ushort* __restrict__ embb,
                                              const float* __restrict__ Wkv,
                                              const float* __restrict__ Wq,
                                              const float* __restrict__ Wo,
                                              ushort* __restrict__ WtAll) {
    const int bid = blockIdx.x;
    if (bid < 2048) {                     // emb f32 -> bf16, 8 elems/thread
        int i = bid * 256 + threadIdx.x;
        const float4* p = (const float4*)emb;
        float4 a = p[2 * i], b = p[2 * i + 1];
        u16x8 r;
        r[0] = f2bf(a.x); r[1] = f2bf(a.y); r[2] = f2bf(a.z); r[3] = f2bf(a.w);
        r[4] = f2bf(b.x); r[5] = f2bf(b.y); r[6] = f2bf(b.z); r[7] = f2bf(b.w);
        ((u16x8*)embb)[i] = r;
        return;
    }
    // transpose W (K=1024 x N) -> WtAll rows [rowofs, rowofs+N) x 1024, bf16
    __shared__ float t[32][33];
    int tb = bid - 2048;
    const float* W; int N, rowofs;
    if (tb < 2048)      { W = Wkv; N = 2048; rowofs = 0; }
    else if (tb < 3072) { W = Wq;  N = 1024; rowofs = 2048; tb -= 2048; }
    else                { W = Wo;  N = 1024; rowofs = 3072; tb -= 3072; }
    const int nbx = N >> 5;
    const int bx = tb % nbx, by = tb / nbx;
    const int tx = threadIdx.x & 31, ty = threadIdx.x >> 5;
    const int bj = bx * 32, bi = by * 32;
#pragma unroll
    for (int i = 0; i < 4; i++) {
        int r = ty + i * 8;
        t[r][tx] = W[(size_t)(bi + r) * N + bj + tx];
    }
    __syncthreads();
#pragma unroll
    for (int i = 0; i < 4; i++) {
        int r = ty + i * 8;
        WtAll[(size_t)(rowofs + bj + r) * 1024 + bi + tx] = f2bf(t[tx][r]);
    }
}

// ---- GEMM: C[M,N] = A[M,K] @ Bt[N,K]^T + bias (128^2, 8-wave, r13) ---------
// 2-phase counted-vmcnt pipeline: STAGE(next) -> vmcnt(2) -> barrier ->
// ds_read+MFMA -> barrier. 512 thr = 8 waves; acc[2][4] (8 MFMA/iter/wave).
// launch_bounds(512,8) pins VGPR<=64 -> 4 blk/CU = 32 waves/CU.
// MODE 3: merged KV+Q epilogue (direct stores, r8).
template <int MODE>
__global__ __launch_bounds__(512, 8) void gemm_bt_k(const ushort* __restrict__ A,
                                                    const ushort* __restrict__ Bt,
                                                    const float* __restrict__ bias,
                                                    const float* __restrict__ bias2,
                                                    void* __restrict__ Cout,
                                                    ushort* __restrict__ Vout,
                                                    ushort* __restrict__ Qout,
                                                    int M, int N, int K) {
    __shared__ __align__(16) char sA[2][8192];
    __shared__ __align__(16) char sB[2][8192];
    const int tid = threadIdx.x;
    const int nbc = N >> 7;
    const int cpx = (gridDim.x >> 3);
    const int swzb = (blockIdx.x & 7) * cpx + (blockIdx.x >> 3);
    const int brow = swzb / nbc, bcol = swzb % nbc;
    const int w = tid >> 6, lane = tid & 63;
    const int wr = w >> 1, wc = w & 1;
    const int lg = lane >> 4, l16 = lane & 15;

    f32x4 acc[2][4] = {};

    const int r0 = tid >> 2;                   // 0..127
    const int sl = (tid & 3) ^ (r0 & 3);       // pre-swizzled global chunk
    const ushort* a0 = A + (size_t)(brow * 128 + r0) * K + sl * 8;
    const ushort* b0 = Bt + (size_t)(bcol * 128 + r0) * K + sl * 8;

    const int arow = wr * 32 + l16;
    const int bcolr = wc * 64 + l16;

    auto STAGE = [&](int buf, int k0) {
        gload16(a0 + k0, sA[buf] + w * 1024);
        gload16(b0 + k0, sB[buf] + w * 1024);
    };

    const int nk = K >> 5;
    STAGE(0, 0);

    for (int k0 = 0; k0 < nk; k0++) {
        const int buf = k0 & 1;
        if (k0 < nk - 1) {
            STAGE(buf ^ 1, (k0 + 1) << 5);
            asm volatile("s_waitcnt vmcnt(2)" ::: "memory");  // tile k0 landed
        } else {
            asm volatile("s_waitcnt vmcnt(0)" ::: "memory");
        }
        __builtin_amdgcn_s_barrier();
        __builtin_amdgcn_sched_barrier(0);

        bf16x8 af[2], bfr[4];
#pragma unroll
        for (int rf = 0; rf < 2; rf++) {
            int rr = arow + rf * 16;
            af[rf] = *(const bf16x8*)(sA[buf] + rr * 64 + ((lg * 16) ^ ((rr & 3) << 4)));
        }
#pragma unroll
        for (int cf = 0; cf < 4; cf++) {
            int rr = bcolr + cf * 16;
            bfr[cf] = *(const bf16x8*)(sB[buf] + rr * 64 + ((lg * 16) ^ ((rr & 3) << 4)));
        }
#pragma unroll
        for (int rf = 0; rf < 2; rf++)
#pragma unroll
            for (int cf = 0; cf < 4; cf++)
                acc[rf][cf] = mfma16(af[rf], bfr[cf], acc[rf][cf]);
        __builtin_amdgcn_s_barrier();     // reads done before buf is re-staged
    }

#pragma unroll
    for (int cf = 0; cf < 4; cf++) {
        const int col = bcol * 128 + wc * 64 + cf * 16 + l16;
        if constexpr (MODE == 3) {
            if (col < 2048) {          // KV region (uniform per block: bcol<16)
                const float bv = bias[col];
                const int h = col >> 7, lo = col & 127;
#pragma unroll
                for (int rf = 0; rf < 2; rf++) {
                    int row = brow * 128 + wr * 32 + rf * 16 + lg * 4;
                    int b = row >> 11, s = row & 2047;
                    if (lo < 64) {   // K -> Kb[bh][s][d]
                        ushort* Kout = (ushort*)Cout;
#pragma unroll
                        for (int r = 0; r < 4; r++)
                            Kout[((size_t)(b * 16 + h) * 2048 + s + r) * 64 + lo] =
                                f2bf(acc[rf][cf][r] + bv);
                    } else {         // V -> Vt[bh][d][s], 4 s-values packed
                        u16x4 pk;
#pragma unroll
                        for (int r = 0; r < 4; r++) pk[r] = f2bf(acc[rf][cf][r] + bv);
                        *(u16x4*)(Vout + ((size_t)(b * 16 + h) * 64 + (lo - 64)) * 2048 + s) = pk;
                    }
                }
            } else {                   // Q region: scale by 0.125*log2e (exp2 fold)
                const int qc = col - 2048;
                const float bv = bias2[qc];
                const float qs = 0.125f * LOG2E;
#pragma unroll
                for (int rf = 0; rf < 2; rf++) {
                    int row = brow * 128 + wr * 32 + rf * 16 + lg * 4;
#pragma unroll
                    for (int r = 0; r < 4; r++)
                        Qout[(size_t)(row + r) * 1024 + qc] =
                            f2bf((acc[rf][cf][r] + bv) * qs);
                }
            }
        } else {
            const float bv = bias[col];
#pragma unroll
            for (int rf = 0; rf < 2; rf++) {
                int row = brow * 128 + wr * 32 + rf * 16 + lg * 4;
#pragma unroll
                for (int r = 0; r < 4; r++) {
                    float v = acc[rf][cf][r] + bv;
                    if (MODE == 1) ((float*)Cout)[(size_t)(row + r) * N + col] = v;
                    else           ((ushort*)Cout)[(size_t)(row + r) * N + col] = f2bf(v);
                }
            }
        }
    }
}

// ---- out-projection GEMM: 128x64 tiles, grid 512 (r14-verified) ------------
__global__ __launch_bounds__(256, 8) void gemm_out_k(const ushort* __restrict__ A,
                                                     const ushort* __restrict__ Bt,
                                                     const float* __restrict__ bias,
                                                     float* __restrict__ Cout,
                                                     int N, int K) {
    __shared__ __align__(16) char sA[2][8192];   // 128 rows x 32 k
    __shared__ __align__(16) char sB[2][4096];   // 64 rows x 32 k
    const int tid = threadIdx.x;
    const int nbc = N >> 6;                       // 16
    const int cpx = (gridDim.x >> 3);             // 512 -> 64 (grid%8==0)
    const int swzb = (blockIdx.x & 7) * cpx + (blockIdx.x >> 3);
    const int brow = swzb / nbc, bcol = swzb % nbc;
    const int w = tid >> 6, lane = tid & 63;
    const int lg = lane >> 4, l16 = lane & 15;

    f32x4 acc[2][4] = {};

    const int r0 = tid >> 2;                   // 0..63
    const int sl = (tid & 3) ^ (r0 & 3);       // pre-swizzled global chunk
    const ushort* a0 = A + (size_t)(brow * 128 + r0) * K + sl * 8;
    const ushort* a1 = A + (size_t)(brow * 128 + 64 + r0) * K + sl * 8;  // (64&3)==0
    const ushort* b0 = Bt + (size_t)(bcol * 64 + r0) * K + sl * 8;

    const int arow = w * 32 + l16;

    auto STAGE = [&](int buf, int k0) {
        gload16(a0 + k0, sA[buf] + w * 1024);
        gload16(a1 + k0, sA[buf] + 4096 + w * 1024);
        gload16(b0 + k0, sB[buf] + w * 1024);
    };

    const int nk = K >> 5;                     // 32
    STAGE(0, 0);

    for (int k0 = 0; k0 < nk; k0++) {
        const int buf = k0 & 1;
        if (k0 < nk - 1) {
            STAGE(buf ^ 1, (k0 + 1) << 5);
            asm volatile("s_waitcnt vmcnt(3)" ::: "memory");  // tile k0 landed
        } else {
            asm volatile("s_waitcnt vmcnt(0)" ::: "memory");
        }
        __builtin_amdgcn_s_barrier();
        __builtin_amdgcn_sched_barrier(0);

        bf16x8 af[2], bfr[4];
#pragma unroll
        for (int rf = 0; rf < 2; rf++) {
            int rr = arow + rf * 16;
            af[rf] = *(const bf16x8*)(sA[buf] + rr * 64 + ((lg * 16) ^ ((rr & 3) << 4)));
        }
#pragma unroll
        for (int cf = 0; cf < 4; cf++) {
            int rr = cf * 16 + l16;
            bfr[cf] = *(const bf16x8*)(sB[buf] + rr * 64 + ((lg * 16) ^ ((rr & 3) << 4)));
        }
#pragma unroll
        for (int rf = 0; rf < 2; rf++)
#pragma unroll
            for (int cf = 0; cf < 4; cf++)
                acc[rf][cf] = mfma16(af[rf], bfr[cf], acc[rf][cf]);
        __builtin_amdgcn_s_barrier();     // reads done before buf is re-staged
    }

#pragma unroll
    for (int cf = 0; cf < 4; cf++) {
        const int col = bcol * 64 + cf * 16 + l16;
        const float bv = bias[col];
#pragma unroll
        for (int rf = 0; rf < 2; rf++) {
            int row = brow * 128 + w * 32 + rf * 16 + lg * 4;
#pragma unroll
            for (int r = 0; r < 4; r++)
                Cout[(size_t)(row + r) * N + col] = acc[rf][cf][r] + bv;
        }
    }
}

// ---- flash attention, KVBLK=128, 8 waves / 256-q blocks (r16) --------------
// Grid 256 = 32 bh x 8 qtiles(256). 8 waves = 4 pairs; pair (w>>1) owns
// 64 q-cols, member (w&1) owns kk chunks {ksub*32 + kh*64} per tile.
// Per-wave body identical to r8; sync skeleton identical. 512 thr stage the
// 32KB tile -> 4 gload16/thread, vmcnt(4). launch_bounds(512,2): VGPR cap
// 128 fits the ~124-reg body (r15's (512,4) capped at 64 -> spill, 443us);
// LDS 66.5KB -> 2 blk/CU = 4 waves/SIMD (2x r8 TLP); K/V fetch halved.
__global__ __launch_bounds__(512, 2) void attn3_k(const ushort* __restrict__ Qg,
                                                  const ushort* __restrict__ Kg,
                                                  const ushort* __restrict__ Vg,
                                                  ushort* __restrict__ ctx) {
    __shared__ __align__(16) char sK[2][16384];  // [128 kk][64 d], 128B rows, XOR-swz
    __shared__ __align__(16) char sV[2][16384];  // [2 kh][64 d][64 kk], 128B rows, XOR-swz
    __shared__ float lx2[512];                   // l exchange (8 q-groups x 64 lanes)
    const int tid = threadIdx.x;
    const int wg = ((blockIdx.x & 7) << 5) | (blockIdx.x >> 3);   // XCD swizzle, 256%8==0
    const int bh = wg >> 3, qt = wg & 7;
    const int b = bh >> 4, h = bh & 15;
    const int w = tid >> 6, lane = tid & 63;
    const int ql = lane & 31, hi = lane >> 5;
    const int ksub = w & 1;          // which 32-kk subchunk (per kh) this wave owns
    const int qq = w >> 1;           // which 64 q-cols this wave pair owns (0..3)

    const ushort* Kh = Kg + (size_t)bh * (Sc * 64);
    const ushort* Vh = Vg + (size_t)bh * (64 * Sc);

    // Q fragments for two 32-col groups (B-operand: col=q, 8 contig d/lane-half)
    const int qrow0 = qt * 256 + qq * 64 + ql;
    bf16x8 qf[2][4];
#pragma unroll
    for (int qg = 0; qg < 2; qg++) {
        const ushort* qp = Qg + ((size_t)(b * Sc + qrow0 + qg * 32)) * Dc + h * HDc + hi * 8;
#pragma unroll
        for (int jd = 0; jd < 4; jd++) qf[qg][jd] = *(const bf16x8*)(qp + jd * 16);
    }

    const int l8 = lane >> 3;                    // row&7 of every staged row
    const int sl = (lane & 7) ^ l8;              // pre-swizzled chunk

    f32x16 o[2][2] = {};     // [dg][qg]
    float l_run[2] = {0.0f, 0.0f};               // row-sum l (f32, per q-group)
    const float MH = 8.0f * LOG2E;
    const int sw = (ql & 7) << 4;                // read-side XOR swizzle

    // staging (512 thr, 4 gload16/thread):
    //  K: rows w*16 + j*8 + l8 (j=0..1) cover 0..127; chunk slot lane&7 holds
    //     global chunk sl = (lane&7)^(row&7); dest sK + w*2048 + j*1024.
    //  V: kh = w>>2; d-rows (w&3)*16 + j*8 + l8 cover 0..63;
    //     dest sV + kh*8192 + (w&3)*2048 + j*1024.
    auto STAGE = [&](int buf, int kt) {
#pragma unroll
        for (int j = 0; j < 2; j++) {
            gload16(Kh + (size_t)(kt * 128 + w * 16 + j * 8 + l8) * 64 + sl * 8,
                    sK[buf] + w * 2048 + j * 1024);
            gload16(Vh + (size_t)((w & 3) * 16 + j * 8 + l8) * Sc +
                        kt * 128 + (w >> 2) * 64 + sl * 8,
                    sV[buf] + (w >> 2) * 8192 + (w & 3) * 2048 + j * 1024);
        }
    };

    int cur = 0;
    STAGE(0, 0);

    constexpr int NT = Sc / 128;     // 16
    for (int kt = 0; kt < NT; kt++) {
        if (kt < NT - 1) {
            STAGE(cur ^ 1, kt + 1);
            asm volatile("s_waitcnt vmcnt(4)" ::: "memory");   // tile kt complete
        } else {
            asm volatile("s_waitcnt vmcnt(0)" ::: "memory");
        }
        __builtin_amdgcn_s_barrier();
        __builtin_amdgcn_sched_barrier(0);

#pragma unroll
        for (int kh = 0; kh < 2; kh++) {
            bf16x8 kf[4];
            {
                const char* kb = sK[cur] + (kh * 64 + ksub * 32 + ql) * 128;
#pragma unroll
                for (int jd = 0; jd < 4; jd++)
                    kf[jd] = *(const bf16x8*)(kb + ((jd * 32 + hi * 16) ^ sw));
            }

            f32x16 st[2];
#pragma unroll
            for (int qg = 0; qg < 2; qg++)
#pragma unroll
                for (int i = 0; i < 16; i++) st[qg][i] = -MH;
            __builtin_amdgcn_s_setprio(1);
#pragma unroll
            for (int qg = 0; qg < 2; qg++)
#pragma unroll
                for (int jd = 0; jd < 4; jd++)
                    st[qg] = mfma32(kf[jd], qf[qg][jd], st[qg]);
            __builtin_amdgcn_s_setprio(0);

#pragma unroll
            for (int qg = 0; qg < 2; qg++)
#pragma unroll
                for (int i = 0; i < 16; i++) st[qg][i] = fexp2(st[qg][i]);

            // row-sum l (VALU): partner lane (hi^1) holds the other 16 rows
#pragma unroll
            for (int qg = 0; qg < 2; qg++) {
                float s = ((st[qg][0] + st[qg][1]) + (st[qg][2] + st[qg][3])) +
                          ((st[qg][4] + st[qg][5]) + (st[qg][6] + st[qg][7])) +
                          (((st[qg][8] + st[qg][9]) + (st[qg][10] + st[qg][11])) +
                           ((st[qg][12] + st[qg][13]) + (st[qg][14] + st[qg][15])));
                l_run[qg] += s + __shfl_xor(s, 32);
            }

            bf16x8 pf[2][2];
#pragma unroll
            for (int qg = 0; qg < 2; qg++) {
                unsigned a0 = cvtpk(st[qg][0],  st[qg][1]);
                unsigned a1 = cvtpk(st[qg][2],  st[qg][3]);
                unsigned a2 = cvtpk(st[qg][4],  st[qg][5]);
                unsigned a3 = cvtpk(st[qg][6],  st[qg][7]);
                swap32(a0, a2); swap32(a1, a3);
                u32x4 f0v = {a0, a1, a2, a3};
                pf[qg][0] = __builtin_bit_cast(bf16x8, f0v);
                unsigned c0 = cvtpk(st[qg][8],  st[qg][9]);
                unsigned c1 = cvtpk(st[qg][10], st[qg][11]);
                unsigned c2 = cvtpk(st[qg][12], st[qg][13]);
                unsigned c3 = cvtpk(st[qg][14], st[qg][15]);
                swap32(c0, c2); swap32(c1, c3);
                u32x4 f1v = {c0, c1, c2, c3};
                pf[qg][1] = __builtin_bit_cast(bf16x8, f1v);
            }

            bf16x8 vf[2][2];   // [dg][ks]
#pragma unroll
            for (int dg = 0; dg < 2; dg++) {
                const char* vb = sV[cur] + kh * 8192 + (dg * 32 + ql) * 128;
#pragma unroll
                for (int ks = 0; ks < 2; ks++)
                    vf[dg][ks] = *(const bf16x8*)(vb + ((ksub * 64 + ks * 32 + hi * 16) ^ sw));
            }

            __builtin_amdgcn_s_setprio(1);
#pragma unroll
            for (int qg = 0; qg < 2; qg++)
#pragma unroll
                for (int ks = 0; ks < 2; ks++) {
                    o[0][qg] = mfma32(vf[0][ks], pf[qg][ks], o[0][qg]);
                    o[1][qg] = mfma32(vf[1][ks], pf[qg][ks], o[1][qg]);
                }
            __builtin_amdgcn_s_setprio(0);
        }

        __builtin_amdgcn_s_barrier();     // protect buffer reuse (no vmem drain)
        cur ^= 1;
    }

    // cross-wave (pair) combine: waves ksub=1 export, ksub=0 reduce + write.
    // Pair qq's 16KB region: qq<2 -> sK half qq; qq>=2 -> sV half (qq-2).
    __syncthreads();                      // full sync before LDS reuse
    float* ox = (float*)((qq < 2 ? (char*)sK : (char*)sV) + (qq & 1) * 16384);
    if (ksub) {
#pragma unroll
        for (int dg = 0; dg < 2; dg++)
#pragma unroll
            for (int qg = 0; qg < 2; qg++)
#pragma unroll
                for (int i = 0; i < 16; i++)
                    ox[((dg * 2 + qg) * 16 + i) * 64 + lane] = o[dg][qg][i];
        lx2[(qq * 2 + 0) * 64 + lane] = l_run[0];
        lx2[(qq * 2 + 1) * 64 + lane] = l_run[1];
    }
    __syncthreads();
    if (!ksub) {
#pragma unroll
        for (int dg = 0; dg < 2; dg++)
#pragma unroll
            for (int qg = 0; qg < 2; qg++)
#pragma unroll
                for (int i = 0; i < 16; i++)
                    o[dg][qg][i] += ox[((dg * 2 + qg) * 16 + i) * 64 + lane];
        const float inv0 = 1.0f / (l_run[0] + lx2[(qq * 2 + 0) * 64 + lane]);
        const float inv1 = 1.0f / (l_run[1] + lx2[(qq * 2 + 1) * 64 + lane]);
#pragma unroll
        for (int qg = 0; qg < 2; qg++) {
            const float inv = qg ? inv1 : inv0;
            ushort* cp = ctx + ((size_t)(b * Sc + qrow0 + qg * 32)) * Dc + h * HDc;
#pragma unroll
            for (int dg = 0; dg < 2; dg++)
#pragma unroll
                for (int g = 0; g < 4; g++) {
                    u16x4 pk;
#pragma unroll
                    for (int r = 0; r < 4; r++)
                        pk[r] = f2bf(o[dg][qg][g * 4 + r] * inv);
                    *(u16x4*)(cp + dg * 32 + g * 8 + hi * 4) = pk;
                }
        }
    }
}

extern "C" void kernel_launch(void* const* d_in, const int* in_sizes, int n_in,
                              void* d_out, int out_size, void* d_ws, size_t ws_size,
                              hipStream_t stream) {
    const float* emb  = (const float*)d_in[0];
    const float* W_kv = (const float*)d_in[1];
    const float* b_kv = (const float*)d_in[2];
    const float* W_q  = (const float*)d_in[3];
    const float* b_q  = (const float*)d_in[4];
    const float* W_o  = (const float*)d_in[5];
    const float* b_o  = (const float*)d_in[6];
    float* out = (float*)d_out;

    const int BS = Bc * Sc;           // 4096 rows
    ushort* embb  = (ushort*)d_ws;                      // 4096x1024
    ushort* wallt = embb  + (size_t)BS * Dc;            // 4096x1024 (Wkv^T|Wq^T|Wo^T)
    ushort* wot   = wallt + (size_t)3 * Dc * Dc;        // alias: rows 3072..4095
    ushort* Kb    = wallt + (size_t)4 * Dc * Dc;        // 32 x 2048 x 64
    ushort* Vtb   = Kb    + (size_t)32 * Sc * HDc;      // 32 x 64 x 2048
    ushort* Qb    = Vtb   + (size_t)32 * Sc * HDc;      // 4096x1024 (pre-scaled)
    ushort* ctxb  = Qb    + (size_t)BS * Dc;            // 4096x1024
    // total ~48 MB of d_ws

    prep_k<<<6144, 256, 0, stream>>>(emb, embb, W_kv, W_q, W_o, wallt);

    // merged KV+Q projection: 128^2 tiles, 8 waves, N = 3072, grid 768 (%8==0)
    gemm_bt_k<3><<<(BS / 128) * (3072 / 128), 512, 0, stream>>>(
        embb, wallt, b_kv, b_q, Kb, Vtb, Qb, BS, 3072, Dc);

    // KVBLK=128 attn: 256 q-rows per block, 8 waves, grid 256 (%8==0)
    attn3_k<<<Bc * Hc * (Sc / 256), 512, 0, stream>>>(Qb, Kb, Vtb, ctxb);

    // out projection: 128x64 tiles, grid 512 (%8==0), 2 blk/CU
    gemm_out_k<<<(BS / 128) * (Dc / 64), 256, 0, stream>>>(
        ctxb, wot, b_o, out, Dc, Dc);
}